// Round 13
// baseline (3850.888 us; speedup 1.0000x reference)
//
#include <hip/hip_runtime.h>

#define BB    256
#define NCH   23
#define TT    19
#define SS    437          // NCH*TT
#define BSR   111872       // BB*SS
#define EMBD  256
#define NHEAD 8
#define DH    32
#define NFREQ 101
#define NFFT  200
#define HOPSZ 100
#define TSLEN 2000
#define HID   1024
#define NDEPTH 4
#define NTOK  28639232     // BSR*EMBD
#define QKVW  768
#define WL    786432       // bf16 weight elements per layer
#define CDL   3584         // cvec/dvec f32 per layer: 768+768+1024+1024

typedef __attribute__((ext_vector_type(8))) __bf16 bf16x8;
typedef __attribute__((ext_vector_type(8))) unsigned short u16x8;
typedef __attribute__((ext_vector_type(4))) float  f32x4;

__device__ __forceinline__ float gelu_f(float x){
    return 0.5f*x*(1.0f + tanhf(0.7978845608028654f*(x + 0.044715f*x*x*x)));
}
__device__ __forceinline__ unsigned short f2b(float f){   // f32 -> bf16 RNE
    unsigned u = __float_as_uint(f);
    return (unsigned short)((u + 0x7FFFu + ((u >> 16) & 1u)) >> 16);
}
__device__ __forceinline__ float b2f(unsigned short h){
    return __uint_as_float(((unsigned)h) << 16);
}

// XCD-bijective tile swizzle (m204)
__device__ __forceinline__ void swz_tile(int& bx, int& by){
    int nx = gridDim.x, nwg = nx * gridDim.y;
    int lid = blockIdx.y * nx + blockIdx.x;
    int q = nwg >> 3, r = nwg & 7;
    int xcd = lid & 7, off = lid >> 3;
    int wgid = (xcd < r ? xcd*(q+1) : r*(q+1) + (xcd-r)*q) + off;
    bx = wgid % nx; by = wgid / nx;
}

// ---------------- DFT table bf16 [256][256], interleaved cos/sin rows --------
__global__ void init_twb(unsigned short* __restrict__ tw){
    int i = blockIdx.x*256 + threadIdx.x;
    if(i >= 256*256) return;
    int n = i >> 8, k = i & 255;
    float v = 0.f;
    if(k < NFFT && n < 2*NFREQ){
        int f = n >> 1;
        int ph = (f * k) % NFFT;
        float ang = 6.283185307179586f * (float)ph / (float)NFFT;
        v = (n & 1) ? sinf(ang) : cosf(ang);
    }
    tw[i] = f2b(v);
}

// posenc table f32 [TT][EMBD]
__global__ void init_pe(float* __restrict__ pe){
    int i = blockIdx.x*256 + threadIdx.x;
    if(i >= TT*EMBD) return;
    int t = i / EMBD, e = i % EMBD;
    int j = e >> 1;
    float div = expf((float)(2*j) * (-9.210340371976184f/256.0f));
    float ang = (float)t * div;
    pe[i] = (e & 1) ? cosf(ang) : sinf(ang);
}

// W_proj -> bf16 transposed+padded [256][128]
__global__ void wprep_proj(const float* __restrict__ Wp, unsigned short* __restrict__ Wt){
    int i = blockIdx.x*256 + threadIdx.x;
    if(i >= 256*128) return;
    int e = i >> 7, k = i & 127;
    Wt[i] = f2b(k < NFREQ ? Wp[(size_t)k*EMBD + e] : 0.f);
}

// qkv weights, ln1-scale FOLDED: wbuf[l][n*256+k] = s_k * W[k][n]
__global__ void wprep_qkv(const float* __restrict__ Wq, const float* __restrict__ Wk,
                          const float* __restrict__ Wv, const float* __restrict__ ln1s,
                          unsigned short* __restrict__ wbuf){
    long i = (long)blockIdx.x*256 + threadIdx.x;
    if(i >= (long)NDEPTH*QKVW*EMBD) return;
    int l = (int)(i / (QKVW*EMBD));
    int rem = (int)(i % (QKVW*EMBD));
    int n = rem >> 8, k = rem & 255;
    const float* W = (n < 256) ? Wq : (n < 512) ? Wk : Wv;
    float s = ln1s[l*EMBD + k];
    wbuf[(size_t)l*WL + rem] = f2b(s * W[(size_t)l*65536 + (size_t)k*256 + (n & 255)]);
}
__global__ void wprep_wo(const float* __restrict__ Wo, unsigned short* __restrict__ wbuf){
    int i = blockIdx.x*256 + threadIdx.x;
    if(i >= NDEPTH*65536) return;
    int l = i >> 16, rem = i & 65535;
    int n = rem >> 8, k = rem & 255;
    wbuf[(size_t)l*WL + 196608 + rem] = f2b(Wo[(size_t)l*65536 + (size_t)k*256 + n]);
}
// W1, ln2-scale FOLDED
__global__ void wprep_w1(const float* __restrict__ W1, const float* __restrict__ ln2s,
                         unsigned short* __restrict__ wbuf){
    long i = (long)blockIdx.x*256 + threadIdx.x;
    if(i >= (long)NDEPTH*262144) return;
    int l = (int)(i >> 18), rem = (int)(i & 262143);
    int n = rem >> 8, k = rem & 255;
    float s = ln2s[l*EMBD + k];
    wbuf[(size_t)l*WL + 262144 + rem] = f2b(s * W1[(size_t)l*262144 + (size_t)k*1024 + n]);
}
__global__ void wprep_w2(const float* __restrict__ W2, unsigned short* __restrict__ wbuf){
    long i = (long)blockIdx.x*256 + threadIdx.x;
    if(i >= (long)NDEPTH*262144) return;
    int l = (int)(i >> 18), rem = (int)(i & 262143);
    int n = rem >> 10, k = rem & 1023;
    wbuf[(size_t)l*WL + 524288 + rem] = f2b(W2[(size_t)l*262144 + (size_t)k*256 + n]);
}

// cvec/dvec per layer: cd[l][0:768]=cq, [768:1536]=dq, [1536:2560]=c1, [2560:3584]=d1
// cq[n]=sum_k s1_k*Wqkv[k][n]; dq[n]=sum_k b1_k*Wqkv[k][n]
// c1[n]=sum_k s2_k*W1[k][n];   d1[n]=sum_k b2_k*W1[k][n] + b1bias[n]
__global__ void prep_cd(const float* __restrict__ Wq, const float* __restrict__ Wk,
                        const float* __restrict__ Wv, const float* __restrict__ W1,
                        const float* __restrict__ ln1s, const float* __restrict__ ln1b,
                        const float* __restrict__ ln2s, const float* __restrict__ ln2b,
                        const float* __restrict__ b1, float* __restrict__ cd){
    int i = blockIdx.x*256 + threadIdx.x;       // 4 * 1792
    if(i >= NDEPTH*1792) return;
    int l = i / 1792, r = i % 1792;
    float c = 0.f, d = 0.f;
    if(r < 768){
        const float* W = (r < 256) ? Wq : (r < 512) ? Wk : Wv;
        int n = r & 255;
        for(int k = 0; k < 256; ++k){
            float w = W[(size_t)l*65536 + (size_t)k*256 + n];
            c = fmaf(ln1s[l*EMBD+k], w, c);
            d = fmaf(ln1b[l*EMBD+k], w, d);
        }
        cd[(size_t)l*CDL + r]       = c;
        cd[(size_t)l*CDL + 768 + r] = d;
    } else {
        int n = r - 768;
        for(int k = 0; k < 256; ++k){
            float w = W1[(size_t)l*262144 + (size_t)k*1024 + n];
            c = fmaf(ln2s[l*EMBD+k], w, c);
            d = fmaf(ln2b[l*EMBD+k], w, d);
        }
        cd[(size_t)l*CDL + 1536 + n] = c;
        cd[(size_t)l*CDL + 2560 + n] = d + b1[l*HID + n];
    }
}

// =============== shared GEMM core (global_load_lds staging) ============
#define GEMM_CORE(A_, B_, K_) \
    f32x4 acc[4][4]; \
    _Pragma("unroll") \
    for(int i=0;i<4;++i) \
        _Pragma("unroll") \
        for(int jj=0;jj<4;++jj) acc[i][jj] = (f32x4){0.f,0.f,0.f,0.f}; \
    const int srow0 = w*32 + (l>>3); \
    const int sgrp  = l & 7; \
    for(int k0 = 0; k0 < (K_); k0 += 64){ \
        _Pragma("unroll") \
        for(int it=0; it<4; ++it){ \
            int row  = srow0 + it*8; \
            int colA = ((sgrp ^ (row & 7)) << 3); \
            const unsigned short* ga = (A_) + (size_t)(m0+row)*(K_) + k0 + colA; \
            const unsigned short* gb = (B_) + (size_t)(n0+row)*(K_) + k0 + colA; \
            __builtin_amdgcn_global_load_lds( \
                (__attribute__((address_space(1))) void*)ga, \
                (__attribute__((address_space(3))) void*)(As + w*2048 + it*512), \
                16, 0, 0); \
            __builtin_amdgcn_global_load_lds( \
                (__attribute__((address_space(1))) void*)gb, \
                (__attribute__((address_space(3))) void*)(Bs + w*2048 + it*512), \
                16, 0, 0); \
        } \
        __syncthreads(); \
        GEMM_MFMA_PHASE \
        __syncthreads(); \
    }

#define GEMM_MFMA_PHASE \
        _Pragma("unroll") \
        for(int kk=0; kk<2; ++kk){ \
            bf16x8 af[4], bfr[4]; \
            _Pragma("unroll") \
            for(int mi=0;mi<4;++mi){ \
                int row = wr*64 + mi*16 + (l & 15); \
                int grp = kk*4 + (l >> 4); \
                af[mi] = *(const bf16x8*)&As[row*64 + ((grp ^ (row&7))<<3)]; \
            } \
            _Pragma("unroll") \
            for(int ni=0;ni<4;++ni){ \
                int row = wc*64 + ni*16 + (l & 15); \
                int grp = kk*4 + (l >> 4); \
                bfr[ni] = *(const bf16x8*)&Bs[row*64 + ((grp ^ (row&7))<<3)]; \
            } \
            _Pragma("unroll") \
            for(int mi=0;mi<4;++mi) \
                _Pragma("unroll") \
                for(int ni=0;ni<4;++ni) \
                    acc[mi][ni] = __builtin_amdgcn_mfma_f32_16x16x32_bf16( \
                        af[mi], bfr[ni], acc[mi][ni], 0, 0, 0); \
        }

// ---------------- general MFMA GEMM ----------------
// MODE 1: Cbf16 = b2f(Cin) + acc + bias        (Wo, W2 mid)
// MODE 4: Cf32  = b2f(Cin) + acc + bias        (W2 final -> o_h)
// MODE 5: Cbf16 = rs*acc - rs*mu*cvec + dvec   (qkv, LN folded)
// MODE 6: Cbf16 = gelu(rs*acc - rs*mu*cvec + dvec)  (W1, LN folded)
template<int MODE>
__global__ __launch_bounds__(256) void gemm_mfma(
    const unsigned short* __restrict__ A, const unsigned short* __restrict__ Bt,
    const float* __restrict__ bias, void* __restrict__ Cv,
    const unsigned short* __restrict__ Cin,
    const float* __restrict__ muv, const float* __restrict__ rsv,
    const float* __restrict__ cvec, const float* __restrict__ dvec,
    int M, int N, int K)
{
    __shared__ __align__(16) unsigned short As[128*64];
    __shared__ __align__(16) unsigned short Bs[128*64];
    const int tid = threadIdx.x;
    const int w = tid >> 6, l = tid & 63;
    int bx, by; swz_tile(bx, by);
    const int m0 = by * 128, n0 = bx * 128;
    const int wr = w >> 1, wc = w & 1;
    GEMM_CORE(A, Bt, K)
    const int cn  = l & 15;
    const int cr4 = (l >> 4) * 4;
    float muT[4][4], rsT[4][4];
    if(MODE == 5 || MODE == 6){
        #pragma unroll
        for(int mi=0;mi<4;++mi)
            #pragma unroll
            for(int r=0;r<4;++r){
                int m = m0 + wr*64 + mi*16 + cr4 + r;
                muT[mi][r] = muv[m];
                rsT[mi][r] = rsv[m];
            }
    }
    #pragma unroll
    for(int ni=0;ni<4;++ni){
        int n = n0 + wc*64 + ni*16 + cn;
        float bn = (MODE==1 || MODE==4) ? bias[n] : 0.f;
        float cv = (MODE==5 || MODE==6) ? cvec[n] : 0.f;
        float dv = (MODE==5 || MODE==6) ? dvec[n] : 0.f;
        #pragma unroll
        for(int mi=0;mi<4;++mi){
            int mB = m0 + wr*64 + mi*16 + cr4;
            #pragma unroll
            for(int r=0;r<4;++r){
                size_t off = (size_t)(mB+r)*N + n;
                float v = acc[mi][ni][r];
                if(MODE == 1){
                    ((unsigned short*)Cv)[off] = f2b(b2f(Cin[off]) + v + bn);
                } else if(MODE == 4){
                    ((float*)Cv)[off] = b2f(Cin[off]) + v + bn;
                } else {
                    float y = rsT[mi][r]*v - rsT[mi][r]*muT[mi][r]*cv + dv;
                    ((unsigned short*)Cv)[off] = f2b(MODE==6 ? gelu_f(y) : y);
                }
            }
        }
    }
}

// ---------------- DFT GEMM: A reg-staged from x (frames fused) --------------
__global__ __launch_bounds__(256) void gemm_dft(
    const float* __restrict__ x, const unsigned short* __restrict__ Bt,
    unsigned short* __restrict__ spec)
{
    const int K = 256;
    __shared__ __align__(16) unsigned short As[128*64];
    __shared__ __align__(16) unsigned short Bs[128*64];
    const int tid = threadIdx.x;
    const int w = tid >> 6, l = tid & 63;
    int bx, by; swz_tile(bx, by);
    const int m0 = by * 128, n0 = bx * 128;
    const int wr = w >> 1, wc = w & 1;
    f32x4 acc[4][4];
    #pragma unroll
    for(int i=0;i<4;++i)
        #pragma unroll
        for(int jj=0;jj<4;++jj) acc[i][jj] = (f32x4){0.f,0.f,0.f,0.f};
    const int sgrp = l & 7;
    for(int k0 = 0; k0 < K; k0 += 64){
        #pragma unroll
        for(int it=0; it<4; ++it){
            int row = w*32 + it*8 + (l>>3);
            int kg  = sgrp ^ (row & 7);
            int kb  = k0 + kg*8;
            int m   = m0 + row;
            int t   = m % TT;
            long bc = m / TT;
            const float* src = x + bc*(long)TSLEN + (long)t*HOPSZ + kb;
            u16x8 v;
            #pragma unroll
            for(int j=0;j<8;++j){
                float f = (kb + j < NFFT) ? src[j] : 0.f;
                v[j] = f2b(f);
            }
            *(u16x8*)&As[row*64 + sgrp*8] = v;
            // B via global_load_lds (swizzled source)
            int colB = (kg << 3);
            const unsigned short* gb = Bt + (size_t)(n0+row)*K + k0 + colB;
            __builtin_amdgcn_global_load_lds(
                (__attribute__((address_space(1))) void*)gb,
                (__attribute__((address_space(3))) void*)(Bs + w*2048 + it*512),
                16, 0, 0);
        }
        __syncthreads();
        GEMM_MFMA_PHASE
        __syncthreads();
    }
    const int cn  = l & 15;
    const int cr4 = (l >> 4) * 4;
    #pragma unroll
    for(int ni=0;ni<4;++ni){
        int n = n0 + wc*64 + ni*16 + cn;
        #pragma unroll
        for(int mi=0;mi<4;++mi){
            int mB = m0 + wr*64 + mi*16 + cr4;
            #pragma unroll
            for(int r=0;r<4;++r){
                float own = acc[mi][ni][r];
                float par = __shfl_xor(own, 1, 64);
                if(!(cn & 1)){
                    float sv = sqrtf(own*own + par*par);
                    spec[(size_t)(mB+r)*128 + (n >> 1)] = f2b(sv);
                }
            }
        }
    }
}

// ---------------- emb GEMM: spec_b @ Wpb + full fused epilogue ---------------
__global__ __launch_bounds__(256) void gemm_emb(
    const unsigned short* __restrict__ A, const unsigned short* __restrict__ Bt,
    const float* __restrict__ bp, const float* __restrict__ ctok,
    const float* __restrict__ pe, const float* __restrict__ noise,
    float* __restrict__ o_emb, float* __restrict__ o_masked,
    float* __restrict__ o_mask, unsigned short* __restrict__ bufH)
{
    const int K = 128, N = 256;
    __shared__ __align__(16) unsigned short As[128*64];
    __shared__ __align__(16) unsigned short Bs[128*64];
    const int tid = threadIdx.x;
    const int w = tid >> 6, l = tid & 63;
    int bx, by; swz_tile(bx, by);
    const int m0 = by * 128, n0 = bx * 128;
    const int wr = w >> 1, wc = w & 1;
    GEMM_CORE(A, Bt, K)
    const int cn  = l & 15;
    const int cr4 = (l >> 4) * 4;
    #pragma unroll
    for(int ni=0;ni<4;++ni){
        int n = n0 + wc*64 + ni*16 + cn;
        float bn = bp[n];
        #pragma unroll
        for(int mi=0;mi<4;++mi){
            int mB = m0 + wr*64 + mi*16 + cr4;
            #pragma unroll
            for(int r=0;r<4;++r){
                int m = mB + r;
                int t = m % TT;
                int c = (m / TT) % NCH;
                size_t off = (size_t)m*EMBD + n;
                float v = acc[mi][ni][r] + bn + ctok[c*EMBD + n] + pe[t*EMBD + n];
                o_emb[off] = v;
                float mn = noise[off];
                bool  msk = mn < 0.9f;
                float md = msk ? 0.f : v;
                bufH[off]     = f2b(md);
                o_masked[off] = md;
                o_mask[off]   = msk ? 1.f : 0.f;
            }
        }
    }
}

// ---------------- per-row LN stats: mu, rstd from bf16 h ---------------------
__global__ __launch_bounds__(256) void row_stats(const unsigned short* __restrict__ X,
    float* __restrict__ muv, float* __restrict__ rsv)
{
    int w = threadIdx.x >> 6, lane = threadIdx.x & 63;
    long row = (long)blockIdx.x*4 + w;
    ushort4 u = *(const ushort4*)(X + row*EMBD + lane*4);
    float x0 = b2f(u.x), x1 = b2f(u.y), x2 = b2f(u.z), x3 = b2f(u.w);
    float sum = x0 + x1 + x2 + x3;
    #pragma unroll
    for(int o=32;o>0;o>>=1) sum += __shfl_xor(sum, o, 64);
    float mu = sum * (1.0f/256.0f);
    float dx = x0-mu, dy = x1-mu, dz = x2-mu, dw = x3-mu;
    float vs = dx*dx + dy*dy + dz*dz + dw*dw;
    #pragma unroll
    for(int o=32;o>0;o>>=1) vs += __shfl_xor(vs, o, 64);
    if(lane == 0){
        muv[row] = mu;
        rsv[row] = rsqrtf(vs*(1.0f/256.0f) + 1e-5f);
    }
}

// ---------------- ctx with fused k-softmax stats -----------------------------
__global__ __launch_bounds__(256) void ctx_kernel(const unsigned short* __restrict__ qkvb,
    float* __restrict__ ctx)
{
    __shared__ float kt[16][DH], vt[16][DH];
    __shared__ float sm[8][32], ss[8][32];
    __shared__ float kmsL[32], kinvL[32];
    int bh = blockIdx.x; int b = bh >> 3, h = bh & 7;
    int tid = threadIdx.x;
    {
        int d = tid & 31, g = tid >> 5;
        const unsigned short* p = qkvb + (size_t)b*SS*QKVW + 256 + h*DH + d;
        float m = -1e30f, s = 0.f;
        for(int n = g; n < SS; n += 8){
            float xv = b2f(p[(size_t)n*QKVW]);
            if(xv > m){ s = s*expf(m-xv) + 1.f; m = xv; }
            else      { s += expf(xv-m); }
        }
        sm[g][d] = m; ss[g][d] = s;
    }
    __syncthreads();
    if(tid < 32){
        float M = sm[0][tid], S = ss[0][tid];
        #pragma unroll
        for(int o = 1; o < 8; ++o){
            float m2 = sm[o][tid], s2 = ss[o][tid];
            if(m2 > M){ S = S*expf(M-m2) + s2; M = m2; }
            else      { S += s2*expf(m2-M); }
        }
        kmsL[tid] = M; kinvL[tid] = 1.0f / S;
    }
    __syncthreads();
    int d = tid >> 3, e4 = (tid & 7) * 4;
    float km = kmsL[d];
    float a0=0,a1=0,a2=0,a3=0;
    for(int n0=0;n0<SS;n0+=16){
        __syncthreads();
        #pragma unroll
        for(int i=0;i<2;++i){
            int e = tid + i*256;
            int nn = e >> 5, dd = e & 31;
            int n = n0 + nn;
            float kv, vv;
            if(n < SS){
                size_t off = ((size_t)(b*SS+n))*QKVW + h*DH + dd;
                kv = b2f(qkvb[off + 256]);
                vv = b2f(qkvb[off + 512]);
            } else { kv = -1e30f; vv = 0.f; }
            kt[nn][dd] = kv; vt[nn][dd] = vv;
        }
        __syncthreads();
        #pragma unroll
        for(int nn=0;nn<16;++nn){
            float ke = expf(kt[nn][d] - km);
            a0 = fmaf(ke, vt[nn][e4+0], a0);
            a1 = fmaf(ke, vt[nn][e4+1], a1);
            a2 = fmaf(ke, vt[nn][e4+2], a2);
            a3 = fmaf(ke, vt[nn][e4+3], a3);
        }
    }
    float inv = kinvL[d];
    float* op = ctx + ((size_t)bh*DH + d)*DH + e4;
    op[0]=a0*inv; op[1]=a1*inv; op[2]=a2*inv; op[3]=a3*inv;
}

// ---------------- per-token q-softmax + att = q @ ctx -> bf16 ----------------
__global__ __launch_bounds__(256) void att_kernel(const unsigned short* __restrict__ qkvb,
    const float* __restrict__ ctx, unsigned short* __restrict__ att)
{
    __shared__ float qs[4][EMBD];
    int w = threadIdx.x >> 6, lane = threadIdx.x & 63;
    int b = blockIdx.y;
    int s = blockIdx.x*4 + w;
    if(s >= SS) return;
    long row = (long)b*SS + s;
    ushort4 qu = *(const ushort4*)(qkvb + (size_t)row*QKVW + lane*4);
    float4 q4 = make_float4(b2f(qu.x), b2f(qu.y), b2f(qu.z), b2f(qu.w));
    float m = fmaxf(fmaxf(q4.x,q4.y), fmaxf(q4.z,q4.w));
    #pragma unroll
    for(int o=1;o<8;o<<=1) m = fmaxf(m, __shfl_xor(m, o, 64));
    float e0 = expf(q4.x-m), e1 = expf(q4.y-m), e2 = expf(q4.z-m), e3 = expf(q4.w-m);
    float ssum = e0+e1+e2+e3;
    #pragma unroll
    for(int o=1;o<8;o<<=1) ssum += __shfl_xor(ssum, o, 64);
    float sc = 0.17677669529663687f / ssum;
    *(float4*)&qs[w][lane*4] = make_float4(e0*sc, e1*sc, e2*sc, e3*sc);
    int head = lane >> 3;
    int ecol = (lane & 7) * 4;
    const float* cb = ctx + ((size_t)(b*NHEAD + head))*DH*DH + ecol;
    float a0=0,a1=0,a2=0,a3=0;
    #pragma unroll
    for(int d=0; d<DH; ++d){
        float qd = qs[w][head*DH + d];
        float4 c4 = *(const float4*)(cb + d*DH);
        a0 = fmaf(qd, c4.x, a0);
        a1 = fmaf(qd, c4.y, a1);
        a2 = fmaf(qd, c4.z, a2);
        a3 = fmaf(qd, c4.w, a3);
    }
    ushort4 o4; o4.x=f2b(a0); o4.y=f2b(a1); o4.z=f2b(a2); o4.w=f2b(a3);
    *(ushort4*)(att + row*EMBD + lane*4) = o4;
}

// ---------------- launch ----------------
extern "C" void kernel_launch(void* const* d_in, const int* in_sizes, int n_in,
                              void* d_out, int out_size, void* d_ws, size_t ws_size,
                              hipStream_t stream)
{
    if(n_in != 18) return;

    const float* x     = (const float*)d_in[0];
    const float* noise = (const float*)d_in[1];
    const float* Wproj = (const float*)d_in[2];
    const float* bproj = (const float*)d_in[3];
    const float* ctok  = (const float*)d_in[4];
    const float* ln1s  = (const float*)d_in[5];
    const float* ln1b  = (const float*)d_in[6];
    const float* Wq    = (const float*)d_in[7];
    const float* Wk    = (const float*)d_in[8];
    const float* Wv    = (const float*)d_in[9];
    const float* Wo    = (const float*)d_in[10];
    const float* bo    = (const float*)d_in[11];
    const float* ln2s  = (const float*)d_in[12];
    const float* ln2b  = (const float*)d_in[13];
    const float* W1    = (const float*)d_in[14];
    const float* b1    = (const float*)d_in[15];
    const float* W2    = (const float*)d_in[16];
    const float* b2    = (const float*)d_in[17];

    char* p = (char*)d_ws;
    unsigned short* bufHb = (unsigned short*)p;           p += (size_t)NTOK*2;
    float* big = (float*)p;                               p += (size_t)NTOK*2*4;
    unsigned short* qkvb   = (unsigned short*)big;        // bf16 [BSR][768]
    unsigned short* hidb   = (unsigned short*)big;        // bf16 [BSR][1024]
    unsigned short* specb  = (unsigned short*)p;          p += (size_t)BSR*128*2;
    unsigned short* attb   = (unsigned short*)p;          p += (size_t)NTOK*2;
    float* muv  = (float*)p;                              p += (size_t)BSR*4;
    float* rsv  = (float*)p;                              p += (size_t)BSR*4;
    float* cdb  = (float*)p;                              p += (size_t)NDEPTH*CDL*4;
    float* ctxb = (float*)p;                              p += (size_t)BB*NHEAD*DH*DH*4;
    float* peb  = (float*)p;                              p += (size_t)TT*EMBD*4;
    unsigned short* twb  = (unsigned short*)p;            p += (size_t)65536*2;
    unsigned short* Wpb  = (unsigned short*)p;            p += (size_t)32768*2;
    unsigned short* wbuf = (unsigned short*)p;            p += (size_t)4*WL*2;
    if(ws_size < (size_t)(p - (char*)d_ws)) return;

    float* out      = (float*)d_out;
    float* o_emb    = out;
    float* o_masked = out + (size_t)NTOK;
    float* o_h      = out + 2*(size_t)NTOK;
    float* o_mask   = out + 3*(size_t)NTOK;

    dim3 blk(256);

    // ---- prep ----
    init_twb<<<256, blk, 0, stream>>>(twb);
    init_pe <<<19,  blk, 0, stream>>>(peb);
    wprep_proj<<<128, blk, 0, stream>>>(Wproj, Wpb);
    wprep_qkv<<<3072, blk, 0, stream>>>(Wq, Wk, Wv, ln1s, wbuf);
    wprep_wo <<<1024, blk, 0, stream>>>(Wo, wbuf);
    wprep_w1 <<<4096, blk, 0, stream>>>(W1, ln2s, wbuf);
    wprep_w2 <<<4096, blk, 0, stream>>>(W2, wbuf);
    prep_cd  <<<28,   blk, 0, stream>>>(Wq, Wk, Wv, W1, ln1s, ln1b, ln2s, ln2b, b1, cdb);

    // ---- front end (frames fused into DFT GEMM) ----
    gemm_dft<<<dim3(2,874), blk, 0, stream>>>(x, twb, specb);
    gemm_emb<<<dim3(2,874), blk, 0, stream>>>(specb, Wpb, bproj, ctok, peb, noise,
                                              o_emb, o_masked, o_mask, bufHb);

    // ---- transformer layers (LN folded into qkv / W1 GEMMs) ----
    for(int l=0;l<NDEPTH;++l){
        unsigned short* wl   = wbuf + (size_t)l*WL;
        unsigned short* Wqkv = wl;             // [768][256], ln1s-folded
        unsigned short* Wot  = wl + 196608;    // [256][256]
        unsigned short* W1t  = wl + 262144;    // [1024][256], ln2s-folded
        unsigned short* W2t  = wl + 524288;    // [256][1024]
        float* cq = cdb + (size_t)l*CDL;
        float* dq = cq + 768;
        float* c1 = cq + 1536;
        float* d1 = cq + 2560;

        row_stats<<<BSR/4, blk, 0, stream>>>(bufHb, muv, rsv);
        gemm_mfma<5><<<dim3(6,874), blk, 0, stream>>>(bufHb, Wqkv, nullptr, qkvb,
                                    nullptr, muv, rsv, cq, dq, BSR, QKVW, EMBD);
        ctx_kernel<<<BB*NHEAD, blk, 0, stream>>>(qkvb, ctxb);
        att_kernel<<<dim3(110, BB), blk, 0, stream>>>(qkvb, ctxb, attb);
        gemm_mfma<1><<<dim3(2,874), blk, 0, stream>>>(attb, Wot, bo + l*EMBD, bufHb,
                                    bufHb, nullptr, nullptr, nullptr, nullptr,
                                    BSR, EMBD, EMBD);
        row_stats<<<BSR/4, blk, 0, stream>>>(bufHb, muv, rsv);
        gemm_mfma<6><<<dim3(8,874), blk, 0, stream>>>(bufHb, W1t, nullptr, hidb,
                                    nullptr, muv, rsv, c1, d1, BSR, HID, EMBD);
        if(l == NDEPTH-1)
            gemm_mfma<4><<<dim3(2,874), blk, 0, stream>>>(hidb, W2t, b2 + l*EMBD, o_h,
                                    bufHb, nullptr, nullptr, nullptr, nullptr,
                                    BSR, EMBD, HID);
        else
            gemm_mfma<1><<<dim3(2,874), blk, 0, stream>>>(hidb, W2t, b2 + l*EMBD, bufHb,
                                    bufHb, nullptr, nullptr, nullptr, nullptr,
                                    BSR, EMBD, HID);
    }
}

// Round 14
// 3135.948 us; speedup vs baseline: 1.2280x; 1.2280x over previous
//
#include <hip/hip_runtime.h>

#define BB    256
#define NCH   23
#define TT    19
#define SS    437          // NCH*TT
#define BSR   111872       // BB*SS
#define EMBD  256
#define NHEAD 8
#define DH    32
#define NFREQ 101
#define NFFT  200
#define HOPSZ 100
#define TSLEN 2000
#define HID   1024
#define NDEPTH 4
#define NTOK  28639232     // BSR*EMBD
#define QKVW  768
#define WL    786432       // bf16 weight elements per layer
#define CDL   3584         // cvec/dvec f32 per layer: 768+768+1024+1024

typedef __attribute__((ext_vector_type(8))) __bf16 bf16x8;
typedef __attribute__((ext_vector_type(8))) unsigned short u16x8;
typedef __attribute__((ext_vector_type(4))) float  f32x4;

__device__ __forceinline__ float gelu_f(float x){
    return 0.5f*x*(1.0f + tanhf(0.7978845608028654f*(x + 0.044715f*x*x*x)));
}
__device__ __forceinline__ unsigned short f2b(float f){   // f32 -> bf16 RNE
    unsigned u = __float_as_uint(f);
    return (unsigned short)((u + 0x7FFFu + ((u >> 16) & 1u)) >> 16);
}
__device__ __forceinline__ float b2f(unsigned short h){
    return __uint_as_float(((unsigned)h) << 16);
}

// XCD-bijective tile swizzle (m204)
__device__ __forceinline__ void swz_tile(int& bx, int& by){
    int nx = gridDim.x, nwg = nx * gridDim.y;
    int lid = blockIdx.y * nx + blockIdx.x;
    int q = nwg >> 3, r = nwg & 7;
    int xcd = lid & 7, off = lid >> 3;
    int wgid = (xcd < r ? xcd*(q+1) : r*(q+1) + (xcd-r)*q) + off;
    bx = wgid % nx; by = wgid / nx;
}

// ---------------- DFT table bf16 [256][256], interleaved cos/sin rows --------
__global__ void init_twb(unsigned short* __restrict__ tw){
    int i = blockIdx.x*256 + threadIdx.x;
    if(i >= 256*256) return;
    int n = i >> 8, k = i & 255;
    float v = 0.f;
    if(k < NFFT && n < 2*NFREQ){
        int f = n >> 1;
        int ph = (f * k) % NFFT;
        float ang = 6.283185307179586f * (float)ph / (float)NFFT;
        v = (n & 1) ? sinf(ang) : cosf(ang);
    }
    tw[i] = f2b(v);
}

// posenc table f32 [TT][EMBD]
__global__ void init_pe(float* __restrict__ pe){
    int i = blockIdx.x*256 + threadIdx.x;
    if(i >= TT*EMBD) return;
    int t = i / EMBD, e = i % EMBD;
    int j = e >> 1;
    float div = expf((float)(2*j) * (-9.210340371976184f/256.0f));
    float ang = (float)t * div;
    pe[i] = (e & 1) ? cosf(ang) : sinf(ang);
}

// W_proj -> bf16 transposed+padded [256][128]
__global__ void wprep_proj(const float* __restrict__ Wp, unsigned short* __restrict__ Wt){
    int i = blockIdx.x*256 + threadIdx.x;
    if(i >= 256*128) return;
    int e = i >> 7, k = i & 127;
    Wt[i] = f2b(k < NFREQ ? Wp[(size_t)k*EMBD + e] : 0.f);
}

// qkv weights, ln1-scale FOLDED: wbuf[l][n*256+k] = s_k * W[k][n]
__global__ void wprep_qkv(const float* __restrict__ Wq, const float* __restrict__ Wk,
                          const float* __restrict__ Wv, const float* __restrict__ ln1s,
                          unsigned short* __restrict__ wbuf){
    long i = (long)blockIdx.x*256 + threadIdx.x;
    if(i >= (long)NDEPTH*QKVW*EMBD) return;
    int l = (int)(i / (QKVW*EMBD));
    int rem = (int)(i % (QKVW*EMBD));
    int n = rem >> 8, k = rem & 255;
    const float* W = (n < 256) ? Wq : (n < 512) ? Wk : Wv;
    float s = ln1s[l*EMBD + k];
    wbuf[(size_t)l*WL + rem] = f2b(s * W[(size_t)l*65536 + (size_t)k*256 + (n & 255)]);
}
__global__ void wprep_wo(const float* __restrict__ Wo, unsigned short* __restrict__ wbuf){
    int i = blockIdx.x*256 + threadIdx.x;
    if(i >= NDEPTH*65536) return;
    int l = i >> 16, rem = i & 65535;
    int n = rem >> 8, k = rem & 255;
    wbuf[(size_t)l*WL + 196608 + rem] = f2b(Wo[(size_t)l*65536 + (size_t)k*256 + n]);
}
// W1, ln2-scale FOLDED
__global__ void wprep_w1(const float* __restrict__ W1, const float* __restrict__ ln2s,
                         unsigned short* __restrict__ wbuf){
    long i = (long)blockIdx.x*256 + threadIdx.x;
    if(i >= (long)NDEPTH*262144) return;
    int l = (int)(i >> 18), rem = (int)(i & 262143);
    int n = rem >> 8, k = rem & 255;
    float s = ln2s[l*EMBD + k];
    wbuf[(size_t)l*WL + 262144 + rem] = f2b(s * W1[(size_t)l*262144 + (size_t)k*1024 + n]);
}
__global__ void wprep_w2(const float* __restrict__ W2, unsigned short* __restrict__ wbuf){
    long i = (long)blockIdx.x*256 + threadIdx.x;
    if(i >= (long)NDEPTH*262144) return;
    int l = (int)(i >> 18), rem = (int)(i & 262143);
    int n = rem >> 10, k = rem & 1023;
    wbuf[(size_t)l*WL + 524288 + rem] = f2b(W2[(size_t)l*262144 + (size_t)k*256 + n]);
}

// cvec/dvec per layer
__global__ void prep_cd(const float* __restrict__ Wq, const float* __restrict__ Wk,
                        const float* __restrict__ Wv, const float* __restrict__ W1,
                        const float* __restrict__ ln1s, const float* __restrict__ ln1b,
                        const float* __restrict__ ln2s, const float* __restrict__ ln2b,
                        const float* __restrict__ b1, float* __restrict__ cd){
    int i = blockIdx.x*256 + threadIdx.x;       // 4 * 1792
    if(i >= NDEPTH*1792) return;
    int l = i / 1792, r = i % 1792;
    float c = 0.f, d = 0.f;
    if(r < 768){
        const float* W = (r < 256) ? Wq : (r < 512) ? Wk : Wv;
        int n = r & 255;
        for(int k = 0; k < 256; ++k){
            float w = W[(size_t)l*65536 + (size_t)k*256 + n];
            c = fmaf(ln1s[l*EMBD+k], w, c);
            d = fmaf(ln1b[l*EMBD+k], w, d);
        }
        cd[(size_t)l*CDL + r]       = c;
        cd[(size_t)l*CDL + 768 + r] = d;
    } else {
        int n = r - 768;
        for(int k = 0; k < 256; ++k){
            float w = W1[(size_t)l*262144 + (size_t)k*1024 + n];
            c = fmaf(ln2s[l*EMBD+k], w, c);
            d = fmaf(ln2b[l*EMBD+k], w, d);
        }
        cd[(size_t)l*CDL + 1536 + n] = c;
        cd[(size_t)l*CDL + 2560 + n] = d + b1[l*HID + n];
    }
}

// =============== shared GEMM core (global_load_lds staging) ============
#define GEMM_CORE(A_, B_, K_) \
    f32x4 acc[4][4]; \
    _Pragma("unroll") \
    for(int i=0;i<4;++i) \
        _Pragma("unroll") \
        for(int jj=0;jj<4;++jj) acc[i][jj] = (f32x4){0.f,0.f,0.f,0.f}; \
    const int srow0 = w*32 + (l>>3); \
    const int sgrp  = l & 7; \
    for(int k0 = 0; k0 < (K_); k0 += 64){ \
        _Pragma("unroll") \
        for(int it=0; it<4; ++it){ \
            int row  = srow0 + it*8; \
            int colA = ((sgrp ^ (row & 7)) << 3); \
            const unsigned short* ga = (A_) + (size_t)(m0+row)*(K_) + k0 + colA; \
            const unsigned short* gb = (B_) + (size_t)(n0+row)*(K_) + k0 + colA; \
            __builtin_amdgcn_global_load_lds( \
                (__attribute__((address_space(1))) void*)ga, \
                (__attribute__((address_space(3))) void*)(As + w*2048 + it*512), \
                16, 0, 0); \
            __builtin_amdgcn_global_load_lds( \
                (__attribute__((address_space(1))) void*)gb, \
                (__attribute__((address_space(3))) void*)(Bs + w*2048 + it*512), \
                16, 0, 0); \
        } \
        __syncthreads(); \
        GEMM_MFMA_PHASE \
        __syncthreads(); \
    }

#define GEMM_MFMA_PHASE \
        _Pragma("unroll") \
        for(int kk=0; kk<2; ++kk){ \
            bf16x8 af[4], bfr[4]; \
            _Pragma("unroll") \
            for(int mi=0;mi<4;++mi){ \
                int row = wr*64 + mi*16 + (l & 15); \
                int grp = kk*4 + (l >> 4); \
                af[mi] = *(const bf16x8*)&As[row*64 + ((grp ^ (row&7))<<3)]; \
            } \
            _Pragma("unroll") \
            for(int ni=0;ni<4;++ni){ \
                int row = wc*64 + ni*16 + (l & 15); \
                int grp = kk*4 + (l >> 4); \
                bfr[ni] = *(const bf16x8*)&Bs[row*64 + ((grp ^ (row&7))<<3)]; \
            } \
            _Pragma("unroll") \
            for(int mi=0;mi<4;++mi) \
                _Pragma("unroll") \
                for(int ni=0;ni<4;++ni) \
                    acc[mi][ni] = __builtin_amdgcn_mfma_f32_16x16x32_bf16( \
                        af[mi], bfr[ni], acc[mi][ni], 0, 0, 0); \
        }

// ---------------- general MFMA GEMM (residual epilogues) ----------------
// MODE 1: Cbf16 = b2f(Cin) + acc + bias        (Wo, W2 mid)
// MODE 4: Cf32  = b2f(Cin) + acc + bias        (W2 final -> o_h)
template<int MODE>
__global__ __launch_bounds__(256) void gemm_mfma(
    const unsigned short* __restrict__ A, const unsigned short* __restrict__ Bt,
    const float* __restrict__ bias, void* __restrict__ Cv,
    const unsigned short* __restrict__ Cin, int M, int N, int K)
{
    __shared__ __align__(16) unsigned short As[128*64];
    __shared__ __align__(16) unsigned short Bs[128*64];
    const int tid = threadIdx.x;
    const int w = tid >> 6, l = tid & 63;
    int bx, by; swz_tile(bx, by);
    const int m0 = by * 128, n0 = bx * 128;
    const int wr = w >> 1, wc = w & 1;
    GEMM_CORE(A, Bt, K)
    const int cn  = l & 15;
    const int cr4 = (l >> 4) * 4;
    #pragma unroll
    for(int ni=0;ni<4;++ni){
        int n = n0 + wc*64 + ni*16 + cn;
        float bn = bias[n];
        #pragma unroll
        for(int mi=0;mi<4;++mi){
            int mB = m0 + wr*64 + mi*16 + cr4;
            #pragma unroll
            for(int r=0;r<4;++r){
                size_t off = (size_t)(mB+r)*N + n;
                float v = acc[mi][ni][r];
                if(MODE == 1)
                    ((unsigned short*)Cv)[off] = f2b(b2f(Cin[off]) + v + bn);
                else
                    ((float*)Cv)[off] = b2f(Cin[off]) + v + bn;
            }
        }
    }
}

// ---------------- LN-folded MFMA GEMM, register-capped -----------------------
// GELU=0: Cbf16 = rs*acc - rs*mu*cvec + dvec          (qkv)
// GELU=1: Cbf16 = gelu(rs*acc - rs*mu*cvec + dvec)    (W1)
// __launch_bounds__(256,4): cap VGPR <=128 -> 4 blocks/CU (r13 ran 136 VGPR, 3/CU)
template<int GELU>
__global__ __launch_bounds__(256, 4) void gemm_ln(
    const unsigned short* __restrict__ A, const unsigned short* __restrict__ Bt,
    void* __restrict__ Cv,
    const float* __restrict__ muv, const float* __restrict__ rsv,
    const float* __restrict__ cvec, const float* __restrict__ dvec,
    int M, int N, int K)
{
    __shared__ __align__(16) unsigned short As[128*64];
    __shared__ __align__(16) unsigned short Bs[128*64];
    const int tid = threadIdx.x;
    const int w = tid >> 6, l = tid & 63;
    int bx, by; swz_tile(bx, by);
    const int m0 = by * 128, n0 = bx * 128;
    const int wr = w >> 1, wc = w & 1;
    GEMM_CORE(A, Bt, K)
    const int cn  = l & 15;
    const int cr4 = (l >> 4) * 4;
    float cv[4], dv[4];
    #pragma unroll
    for(int ni=0;ni<4;++ni){
        int n = n0 + wc*64 + ni*16 + cn;
        cv[ni] = cvec[n]; dv[ni] = dvec[n];
    }
    #pragma unroll
    for(int mi=0;mi<4;++mi){
        #pragma unroll
        for(int r=0;r<4;++r){
            int m = m0 + wr*64 + mi*16 + cr4 + r;
            float mu = muv[m], rs = rsv[m];
            float c0 = rs * mu;
            #pragma unroll
            for(int ni=0;ni<4;++ni){
                int n = n0 + wc*64 + ni*16 + cn;
                float y = rs*acc[mi][ni][r] - c0*cv[ni] + dv[ni];
                ((unsigned short*)Cv)[(size_t)m*N + n] = f2b(GELU ? gelu_f(y) : y);
            }
        }
    }
}

// ---------------- DFT GEMM: A reg-staged from x (frames fused) --------------
__global__ __launch_bounds__(256) void gemm_dft(
    const float* __restrict__ x, const unsigned short* __restrict__ Bt,
    unsigned short* __restrict__ spec)
{
    const int K = 256;
    __shared__ __align__(16) unsigned short As[128*64];
    __shared__ __align__(16) unsigned short Bs[128*64];
    const int tid = threadIdx.x;
    const int w = tid >> 6, l = tid & 63;
    int bx, by; swz_tile(bx, by);
    const int m0 = by * 128, n0 = bx * 128;
    const int wr = w >> 1, wc = w & 1;
    f32x4 acc[4][4];
    #pragma unroll
    for(int i=0;i<4;++i)
        #pragma unroll
        for(int jj=0;jj<4;++jj) acc[i][jj] = (f32x4){0.f,0.f,0.f,0.f};
    const int sgrp = l & 7;
    for(int k0 = 0; k0 < K; k0 += 64){
        #pragma unroll
        for(int it=0; it<4; ++it){
            int row = w*32 + it*8 + (l>>3);
            int kg  = sgrp ^ (row & 7);
            int kb  = k0 + kg*8;
            int m   = m0 + row;
            int t   = m % TT;
            long bc = m / TT;
            const float* src = x + bc*(long)TSLEN + (long)t*HOPSZ + kb;
            u16x8 v;
            #pragma unroll
            for(int j=0;j<8;++j){
                float f = (kb + j < NFFT) ? src[j] : 0.f;
                v[j] = f2b(f);
            }
            *(u16x8*)&As[row*64 + sgrp*8] = v;
            int colB = (kg << 3);
            const unsigned short* gb = Bt + (size_t)(n0+row)*K + k0 + colB;
            __builtin_amdgcn_global_load_lds(
                (__attribute__((address_space(1))) void*)gb,
                (__attribute__((address_space(3))) void*)(Bs + w*2048 + it*512),
                16, 0, 0);
        }
        __syncthreads();
        GEMM_MFMA_PHASE
        __syncthreads();
    }
    const int cn  = l & 15;
    const int cr4 = (l >> 4) * 4;
    #pragma unroll
    for(int ni=0;ni<4;++ni){
        int n = n0 + wc*64 + ni*16 + cn;
        #pragma unroll
        for(int mi=0;mi<4;++mi){
            int mB = m0 + wr*64 + mi*16 + cr4;
            #pragma unroll
            for(int r=0;r<4;++r){
                float own = acc[mi][ni][r];
                float par = __shfl_xor(own, 1, 64);
                if(!(cn & 1)){
                    float sv = sqrtf(own*own + par*par);
                    spec[(size_t)(mB+r)*128 + (n >> 1)] = f2b(sv);
                }
            }
        }
    }
}

// ---------------- emb GEMM: spec_b @ Wpb + full fused epilogue ---------------
__global__ __launch_bounds__(256) void gemm_emb(
    const unsigned short* __restrict__ A, const unsigned short* __restrict__ Bt,
    const float* __restrict__ bp, const float* __restrict__ ctok,
    const float* __restrict__ pe, const float* __restrict__ noise,
    float* __restrict__ o_emb, float* __restrict__ o_masked,
    float* __restrict__ o_mask, unsigned short* __restrict__ bufH)
{
    const int K = 128, N = 256;
    __shared__ __align__(16) unsigned short As[128*64];
    __shared__ __align__(16) unsigned short Bs[128*64];
    const int tid = threadIdx.x;
    const int w = tid >> 6, l = tid & 63;
    int bx, by; swz_tile(bx, by);
    const int m0 = by * 128, n0 = bx * 128;
    const int wr = w >> 1, wc = w & 1;
    GEMM_CORE(A, Bt, K)
    const int cn  = l & 15;
    const int cr4 = (l >> 4) * 4;
    #pragma unroll
    for(int ni=0;ni<4;++ni){
        int n = n0 + wc*64 + ni*16 + cn;
        float bn = bp[n];
        #pragma unroll
        for(int mi=0;mi<4;++mi){
            int mB = m0 + wr*64 + mi*16 + cr4;
            #pragma unroll
            for(int r=0;r<4;++r){
                int m = mB + r;
                int t = m % TT;
                int c = (m / TT) % NCH;
                size_t off = (size_t)m*EMBD + n;
                float v = acc[mi][ni][r] + bn + ctok[c*EMBD + n] + pe[t*EMBD + n];
                o_emb[off] = v;
                float mn = noise[off];
                bool  msk = mn < 0.9f;
                float md = msk ? 0.f : v;
                bufH[off]     = f2b(md);
                o_masked[off] = md;
                o_mask[off]   = msk ? 1.f : 0.f;
            }
        }
    }
}

// ---------------- per-row LN stats: mu, rstd from bf16 h ---------------------
__global__ __launch_bounds__(256) void row_stats(const unsigned short* __restrict__ X,
    float* __restrict__ muv, float* __restrict__ rsv)
{
    int w = threadIdx.x >> 6, lane = threadIdx.x & 63;
    long row = (long)blockIdx.x*4 + w;
    ushort4 u = *(const ushort4*)(X + row*EMBD + lane*4);
    float x0 = b2f(u.x), x1 = b2f(u.y), x2 = b2f(u.z), x3 = b2f(u.w);
    float sum = x0 + x1 + x2 + x3;
    #pragma unroll
    for(int o=32;o>0;o>>=1) sum += __shfl_xor(sum, o, 64);
    float mu = sum * (1.0f/256.0f);
    float dx = x0-mu, dy = x1-mu, dz = x2-mu, dw = x3-mu;
    float vs = dx*dx + dy*dy + dz*dz + dw*dw;
    #pragma unroll
    for(int o=32;o>0;o>>=1) vs += __shfl_xor(vs, o, 64);
    if(lane == 0){
        muv[row] = mu;
        rsv[row] = rsqrtf(vs*(1.0f/256.0f) + 1e-5f);
    }
}

// ---------------- ctx with fused k-softmax stats -----------------------------
__global__ __launch_bounds__(256) void ctx_kernel(const unsigned short* __restrict__ qkvb,
    float* __restrict__ ctx)
{
    __shared__ float kt[16][DH], vt[16][DH];
    __shared__ float sm[8][32], ss[8][32];
    __shared__ float kmsL[32], kinvL[32];
    int bh = blockIdx.x; int b = bh >> 3, h = bh & 7;
    int tid = threadIdx.x;
    {
        int d = tid & 31, g = tid >> 5;
        const unsigned short* p = qkvb + (size_t)b*SS*QKVW + 256 + h*DH + d;
        float m = -1e30f, s = 0.f;
        for(int n = g; n < SS; n += 8){
            float xv = b2f(p[(size_t)n*QKVW]);
            if(xv > m){ s = s*expf(m-xv) + 1.f; m = xv; }
            else      { s += expf(xv-m); }
        }
        sm[g][d] = m; ss[g][d] = s;
    }
    __syncthreads();
    if(tid < 32){
        float M = sm[0][tid], S = ss[0][tid];
        #pragma unroll
        for(int o = 1; o < 8; ++o){
            float m2 = sm[o][tid], s2 = ss[o][tid];
            if(m2 > M){ S = S*expf(M-m2) + s2; M = m2; }
            else      { S += s2*expf(m2-M); }
        }
        kmsL[tid] = M; kinvL[tid] = 1.0f / S;
    }
    __syncthreads();
    int d = tid >> 3, e4 = (tid & 7) * 4;
    float km = kmsL[d];
    float a0=0,a1=0,a2=0,a3=0;
    for(int n0=0;n0<SS;n0+=16){
        __syncthreads();
        #pragma unroll
        for(int i=0;i<2;++i){
            int e = tid + i*256;
            int nn = e >> 5, dd = e & 31;
            int n = n0 + nn;
            float kv, vv;
            if(n < SS){
                size_t off = ((size_t)(b*SS+n))*QKVW + h*DH + dd;
                kv = b2f(qkvb[off + 256]);
                vv = b2f(qkvb[off + 512]);
            } else { kv = -1e30f; vv = 0.f; }
            kt[nn][dd] = kv; vt[nn][dd] = vv;
        }
        __syncthreads();
        #pragma unroll
        for(int nn=0;nn<16;++nn){
            float ke = expf(kt[nn][d] - km);
            a0 = fmaf(ke, vt[nn][e4+0], a0);
            a1 = fmaf(ke, vt[nn][e4+1], a1);
            a2 = fmaf(ke, vt[nn][e4+2], a2);
            a3 = fmaf(ke, vt[nn][e4+3], a3);
        }
    }
    float inv = kinvL[d];
    float* op = ctx + ((size_t)bh*DH + d)*DH + e4;
    op[0]=a0*inv; op[1]=a1*inv; op[2]=a2*inv; op[3]=a3*inv;
}

// ---------------- per-token q-softmax + att = q @ ctx -> bf16 ----------------
__global__ __launch_bounds__(256) void att_kernel(const unsigned short* __restrict__ qkvb,
    const float* __restrict__ ctx, unsigned short* __restrict__ att)
{
    __shared__ float qs[4][EMBD];
    int w = threadIdx.x >> 6, lane = threadIdx.x & 63;
    int b = blockIdx.y;
    int s = blockIdx.x*4 + w;
    if(s >= SS) return;
    long row = (long)b*SS + s;
    ushort4 qu = *(const ushort4*)(qkvb + (size_t)row*QKVW + lane*4);
    float4 q4 = make_float4(b2f(qu.x), b2f(qu.y), b2f(qu.z), b2f(qu.w));
    float m = fmaxf(fmaxf(q4.x,q4.y), fmaxf(q4.z,q4.w));
    #pragma unroll
    for(int o=1;o<8;o<<=1) m = fmaxf(m, __shfl_xor(m, o, 64));
    float e0 = expf(q4.x-m), e1 = expf(q4.y-m), e2 = expf(q4.z-m), e3 = expf(q4.w-m);
    float ssum = e0+e1+e2+e3;
    #pragma unroll
    for(int o=1;o<8;o<<=1) ssum += __shfl_xor(ssum, o, 64);
    float sc = 0.17677669529663687f / ssum;
    *(float4*)&qs[w][lane*4] = make_float4(e0*sc, e1*sc, e2*sc, e3*sc);
    int head = lane >> 3;
    int ecol = (lane & 7) * 4;
    const float* cb = ctx + ((size_t)(b*NHEAD + head))*DH*DH + ecol;
    float a0=0,a1=0,a2=0,a3=0;
    #pragma unroll
    for(int d=0; d<DH; ++d){
        float qd = qs[w][head*DH + d];
        float4 c4 = *(const float4*)(cb + d*DH);
        a0 = fmaf(qd, c4.x, a0);
        a1 = fmaf(qd, c4.y, a1);
        a2 = fmaf(qd, c4.z, a2);
        a3 = fmaf(qd, c4.w, a3);
    }
    ushort4 o4; o4.x=f2b(a0); o4.y=f2b(a1); o4.z=f2b(a2); o4.w=f2b(a3);
    *(ushort4*)(att + row*EMBD + lane*4) = o4;
}

// ---------------- launch ----------------
extern "C" void kernel_launch(void* const* d_in, const int* in_sizes, int n_in,
                              void* d_out, int out_size, void* d_ws, size_t ws_size,
                              hipStream_t stream)
{
    if(n_in != 18) return;

    const float* x     = (const float*)d_in[0];
    const float* noise = (const float*)d_in[1];
    const float* Wproj = (const float*)d_in[2];
    const float* bproj = (const float*)d_in[3];
    const float* ctok  = (const float*)d_in[4];
    const float* ln1s  = (const float*)d_in[5];
    const float* ln1b  = (const float*)d_in[6];
    const float* Wq    = (const float*)d_in[7];
    const float* Wk    = (const float*)d_in[8];
    const float* Wv    = (const float*)d_in[9];
    const float* Wo    = (const float*)d_in[10];
    const float* bo    = (const float*)d_in[11];
    const float* ln2s  = (const float*)d_in[12];
    const float* ln2b  = (const float*)d_in[13];
    const float* W1    = (const float*)d_in[14];
    const float* b1    = (const float*)d_in[15];
    const float* W2    = (const float*)d_in[16];
    const float* b2    = (const float*)d_in[17];

    char* p = (char*)d_ws;
    unsigned short* bufHb = (unsigned short*)p;           p += (size_t)NTOK*2;
    float* big = (float*)p;                               p += (size_t)NTOK*2*4;
    unsigned short* qkvb   = (unsigned short*)big;        // bf16 [BSR][768]
    unsigned short* hidb   = (unsigned short*)big;        // bf16 [BSR][1024]
    unsigned short* specb  = (unsigned short*)p;          p += (size_t)BSR*128*2;
    unsigned short* attb   = (unsigned short*)p;          p += (size_t)NTOK*2;
    float* muv  = (float*)p;                              p += (size_t)BSR*4;
    float* rsv  = (float*)p;                              p += (size_t)BSR*4;
    float* cdb  = (float*)p;                              p += (size_t)NDEPTH*CDL*4;
    float* ctxb = (float*)p;                              p += (size_t)BB*NHEAD*DH*DH*4;
    float* peb  = (float*)p;                              p += (size_t)TT*EMBD*4;
    unsigned short* twb  = (unsigned short*)p;            p += (size_t)65536*2;
    unsigned short* Wpb  = (unsigned short*)p;            p += (size_t)32768*2;
    unsigned short* wbuf = (unsigned short*)p;            p += (size_t)4*WL*2;
    if(ws_size < (size_t)(p - (char*)d_ws)) return;

    float* out      = (float*)d_out;
    float* o_emb    = out;
    float* o_masked = out + (size_t)NTOK;
    float* o_h      = out + 2*(size_t)NTOK;
    float* o_mask   = out + 3*(size_t)NTOK;

    dim3 blk(256);

    // ---- prep ----
    init_twb<<<256, blk, 0, stream>>>(twb);
    init_pe <<<19,  blk, 0, stream>>>(peb);
    wprep_proj<<<128, blk, 0, stream>>>(Wproj, Wpb);
    wprep_qkv<<<3072, blk, 0, stream>>>(Wq, Wk, Wv, ln1s, wbuf);
    wprep_wo <<<1024, blk, 0, stream>>>(Wo, wbuf);
    wprep_w1 <<<4096, blk, 0, stream>>>(W1, ln2s, wbuf);
    wprep_w2 <<<4096, blk, 0, stream>>>(W2, wbuf);
    prep_cd  <<<28,   blk, 0, stream>>>(Wq, Wk, Wv, W1, ln1s, ln1b, ln2s, ln2b, b1, cdb);

    // ---- front end ----
    gemm_dft<<<dim3(2,874), blk, 0, stream>>>(x, twb, specb);
    gemm_emb<<<dim3(2,874), blk, 0, stream>>>(specb, Wpb, bproj, ctok, peb, noise,
                                              o_emb, o_masked, o_mask, bufHb);

    // ---- transformer layers (LN folded; gemm_ln register-capped) ----
    for(int l=0;l<NDEPTH;++l){
        unsigned short* wl   = wbuf + (size_t)l*WL;
        unsigned short* Wqkv = wl;             // [768][256], ln1s-folded
        unsigned short* Wot  = wl + 196608;    // [256][256]
        unsigned short* W1t  = wl + 262144;    // [1024][256], ln2s-folded
        unsigned short* W2t  = wl + 524288;    // [256][1024]
        float* cq = cdb + (size_t)l*CDL;
        float* dq = cq + 768;
        float* c1 = cq + 1536;
        float* d1 = cq + 2560;

        row_stats<<<BSR/4, blk, 0, stream>>>(bufHb, muv, rsv);
        gemm_ln<0><<<dim3(6,874), blk, 0, stream>>>(bufHb, Wqkv, qkvb,
                                    muv, rsv, cq, dq, BSR, QKVW, EMBD);
        ctx_kernel<<<BB*NHEAD, blk, 0, stream>>>(qkvb, ctxb);
        att_kernel<<<dim3(110, BB), blk, 0, stream>>>(qkvb, ctxb, attb);
        gemm_mfma<1><<<dim3(2,874), blk, 0, stream>>>(attb, Wot, bo + l*EMBD, bufHb,
                                    bufHb, BSR, EMBD, EMBD);
        row_stats<<<BSR/4, blk, 0, stream>>>(bufHb, muv, rsv);
        gemm_ln<1><<<dim3(8,874), blk, 0, stream>>>(bufHb, W1t, hidb,
                                    muv, rsv, c1, d1, BSR, HID, EMBD);
        if(l == NDEPTH-1)
            gemm_mfma<4><<<dim3(2,874), blk, 0, stream>>>(hidb, W2t, b2 + l*EMBD, o_h,
                                    bufHb, BSR, EMBD, HID);
        else
            gemm_mfma<1><<<dim3(2,874), blk, 0, stream>>>(hidb, W2t, b2 + l*EMBD, bufHb,
                                    bufHb, BSR, EMBD, HID);
    }
}

// Round 15
// 2958.494 us; speedup vs baseline: 1.3016x; 1.0600x over previous
//
#include <hip/hip_runtime.h>

#define BB    256
#define NCH   23
#define TT    19
#define SS    437          // NCH*TT
#define BSR   111872       // BB*SS
#define EMBD  256
#define NHEAD 8
#define DH    32
#define NFREQ 101
#define NFFT  200
#define HOPSZ 100
#define TSLEN 2000
#define HID   1024
#define NDEPTH 4
#define NTOK  28639232     // BSR*EMBD
#define QKVW  768
#define WL    786432       // bf16 weight elements per layer
#define CDL   3584         // cvec/dvec f32 per layer: 768+768+1024+1024

typedef __attribute__((ext_vector_type(8))) __bf16 bf16x8;
typedef __attribute__((ext_vector_type(8))) unsigned short u16x8;
typedef __attribute__((ext_vector_type(4))) float  f32x4;

__device__ __forceinline__ float gelu_f(float x){
    return 0.5f*x*(1.0f + tanhf(0.7978845608028654f*(x + 0.044715f*x*x*x)));
}
__device__ __forceinline__ unsigned short f2b(float f){   // f32 -> bf16 RNE
    unsigned u = __float_as_uint(f);
    return (unsigned short)((u + 0x7FFFu + ((u >> 16) & 1u)) >> 16);
}
__device__ __forceinline__ float b2f(unsigned short h){
    return __uint_as_float(((unsigned)h) << 16);
}

// XCD-bijective tile swizzle (m204)
__device__ __forceinline__ void swz_tile(int& bx, int& by){
    int nx = gridDim.x, nwg = nx * gridDim.y;
    int lid = blockIdx.y * nx + blockIdx.x;
    int q = nwg >> 3, r = nwg & 7;
    int xcd = lid & 7, off = lid >> 3;
    int wgid = (xcd < r ? xcd*(q+1) : r*(q+1) + (xcd-r)*q) + off;
    bx = wgid % nx; by = wgid / nx;
}

// ---------------- DFT table bf16 [256][256], interleaved cos/sin rows --------
__global__ void init_twb(unsigned short* __restrict__ tw){
    int i = blockIdx.x*256 + threadIdx.x;
    if(i >= 256*256) return;
    int n = i >> 8, k = i & 255;
    float v = 0.f;
    if(k < NFFT && n < 2*NFREQ){
        int f = n >> 1;
        int ph = (f * k) % NFFT;
        float ang = 6.283185307179586f * (float)ph / (float)NFFT;
        v = (n & 1) ? sinf(ang) : cosf(ang);
    }
    tw[i] = f2b(v);
}

// posenc table f32 [TT][EMBD]
__global__ void init_pe(float* __restrict__ pe){
    int i = blockIdx.x*256 + threadIdx.x;
    if(i >= TT*EMBD) return;
    int t = i / EMBD, e = i % EMBD;
    int j = e >> 1;
    float div = expf((float)(2*j) * (-9.210340371976184f/256.0f));
    float ang = (float)t * div;
    pe[i] = (e & 1) ? cosf(ang) : sinf(ang);
}

// W_proj -> bf16 transposed+padded [256][128]
__global__ void wprep_proj(const float* __restrict__ Wp, unsigned short* __restrict__ Wt){
    int i = blockIdx.x*256 + threadIdx.x;
    if(i >= 256*128) return;
    int e = i >> 7, k = i & 127;
    Wt[i] = f2b(k < NFREQ ? Wp[(size_t)k*EMBD + e] : 0.f);
}

// qkv weights, ln1-scale FOLDED: wbuf[l][n*256+k] = s_k * W[k][n]
__global__ void wprep_qkv(const float* __restrict__ Wq, const float* __restrict__ Wk,
                          const float* __restrict__ Wv, const float* __restrict__ ln1s,
                          unsigned short* __restrict__ wbuf){
    long i = (long)blockIdx.x*256 + threadIdx.x;
    if(i >= (long)NDEPTH*QKVW*EMBD) return;
    int l = (int)(i / (QKVW*EMBD));
    int rem = (int)(i % (QKVW*EMBD));
    int n = rem >> 8, k = rem & 255;
    const float* W = (n < 256) ? Wq : (n < 512) ? Wk : Wv;
    float s = ln1s[l*EMBD + k];
    wbuf[(size_t)l*WL + rem] = f2b(s * W[(size_t)l*65536 + (size_t)k*256 + (n & 255)]);
}
__global__ void wprep_wo(const float* __restrict__ Wo, unsigned short* __restrict__ wbuf){
    int i = blockIdx.x*256 + threadIdx.x;
    if(i >= NDEPTH*65536) return;
    int l = i >> 16, rem = i & 65535;
    int n = rem >> 8, k = rem & 255;
    wbuf[(size_t)l*WL + 196608 + rem] = f2b(Wo[(size_t)l*65536 + (size_t)k*256 + n]);
}
// W1, ln2-scale FOLDED
__global__ void wprep_w1(const float* __restrict__ W1, const float* __restrict__ ln2s,
                         unsigned short* __restrict__ wbuf){
    long i = (long)blockIdx.x*256 + threadIdx.x;
    if(i >= (long)NDEPTH*262144) return;
    int l = (int)(i >> 18), rem = (int)(i & 262143);
    int n = rem >> 8, k = rem & 255;
    float s = ln2s[l*EMBD + k];
    wbuf[(size_t)l*WL + 262144 + rem] = f2b(s * W1[(size_t)l*262144 + (size_t)k*1024 + n]);
}
__global__ void wprep_w2(const float* __restrict__ W2, unsigned short* __restrict__ wbuf){
    long i = (long)blockIdx.x*256 + threadIdx.x;
    if(i >= (long)NDEPTH*262144) return;
    int l = (int)(i >> 18), rem = (int)(i & 262143);
    int n = rem >> 10, k = rem & 1023;
    wbuf[(size_t)l*WL + 524288 + rem] = f2b(W2[(size_t)l*262144 + (size_t)k*256 + n]);
}

// cvec/dvec per layer
__global__ void prep_cd(const float* __restrict__ Wq, const float* __restrict__ Wk,
                        const float* __restrict__ Wv, const float* __restrict__ W1,
                        const float* __restrict__ ln1s, const float* __restrict__ ln1b,
                        const float* __restrict__ ln2s, const float* __restrict__ ln2b,
                        const float* __restrict__ b1, float* __restrict__ cd){
    int i = blockIdx.x*256 + threadIdx.x;       // 4 * 1792
    if(i >= NDEPTH*1792) return;
    int l = i / 1792, r = i % 1792;
    float c = 0.f, d = 0.f;
    if(r < 768){
        const float* W = (r < 256) ? Wq : (r < 512) ? Wk : Wv;
        int n = r & 255;
        for(int k = 0; k < 256; ++k){
            float w = W[(size_t)l*65536 + (size_t)k*256 + n];
            c = fmaf(ln1s[l*EMBD+k], w, c);
            d = fmaf(ln1b[l*EMBD+k], w, d);
        }
        cd[(size_t)l*CDL + r]       = c;
        cd[(size_t)l*CDL + 768 + r] = d;
    } else {
        int n = r - 768;
        for(int k = 0; k < 256; ++k){
            float w = W1[(size_t)l*262144 + (size_t)k*1024 + n];
            c = fmaf(ln2s[l*EMBD+k], w, c);
            d = fmaf(ln2b[l*EMBD+k], w, d);
        }
        cd[(size_t)l*CDL + 1536 + n] = c;
        cd[(size_t)l*CDL + 2560 + n] = d + b1[l*HID + n];
    }
}

// =============== shared GEMM core (global_load_lds staging) ============
#define GEMM_CORE(A_, B_, K_) \
    f32x4 acc[4][4]; \
    _Pragma("unroll") \
    for(int i=0;i<4;++i) \
        _Pragma("unroll") \
        for(int jj=0;jj<4;++jj) acc[i][jj] = (f32x4){0.f,0.f,0.f,0.f}; \
    const int srow0 = w*32 + (l>>3); \
    const int sgrp  = l & 7; \
    for(int k0 = 0; k0 < (K_); k0 += 64){ \
        _Pragma("unroll") \
        for(int it=0; it<4; ++it){ \
            int row  = srow0 + it*8; \
            int colA = ((sgrp ^ (row & 7)) << 3); \
            const unsigned short* ga = (A_) + (size_t)(m0+row)*(K_) + k0 + colA; \
            const unsigned short* gb = (B_) + (size_t)(n0+row)*(K_) + k0 + colA; \
            __builtin_amdgcn_global_load_lds( \
                (__attribute__((address_space(1))) void*)ga, \
                (__attribute__((address_space(3))) void*)(As + w*2048 + it*512), \
                16, 0, 0); \
            __builtin_amdgcn_global_load_lds( \
                (__attribute__((address_space(1))) void*)gb, \
                (__attribute__((address_space(3))) void*)(Bs + w*2048 + it*512), \
                16, 0, 0); \
        } \
        __syncthreads(); \
        GEMM_MFMA_PHASE \
        __syncthreads(); \
    }

#define GEMM_MFMA_PHASE \
        _Pragma("unroll") \
        for(int kk=0; kk<2; ++kk){ \
            bf16x8 af[4], bfr[4]; \
            _Pragma("unroll") \
            for(int mi=0;mi<4;++mi){ \
                int row = wr*64 + mi*16 + (l & 15); \
                int grp = kk*4 + (l >> 4); \
                af[mi] = *(const bf16x8*)&As[row*64 + ((grp ^ (row&7))<<3)]; \
            } \
            _Pragma("unroll") \
            for(int ni=0;ni<4;++ni){ \
                int row = wc*64 + ni*16 + (l & 15); \
                int grp = kk*4 + (l >> 4); \
                bfr[ni] = *(const bf16x8*)&Bs[row*64 + ((grp ^ (row&7))<<3)]; \
            } \
            _Pragma("unroll") \
            for(int mi=0;mi<4;++mi) \
                _Pragma("unroll") \
                for(int ni=0;ni<4;++ni) \
                    acc[mi][ni] = __builtin_amdgcn_mfma_f32_16x16x32_bf16( \
                        af[mi], bfr[ni], acc[mi][ni], 0, 0, 0); \
        }

// stats helper: per-row {sum, sumsq} block-reduce + 2-contributor atomics
#define STATS_REDUCE_STORE(rb_, s1_, s2_) \
    { \
        _Pragma("unroll") \
        for(int o=1;o<16;o<<=1){ s1_ += __shfl_xor(s1_, o, 64); s2_ += __shfl_xor(s2_, o, 64); } \
        if(cn == 0){ \
            slds[((rb_)*2 + wc)*2 + 0] = s1_; \
            slds[((rb_)*2 + wc)*2 + 1] = s2_; \
        } \
    }

// ---------------- general MFMA GEMM (residual epilogues) ----------------
// MODE 1: Cbf16 = b2f(Cin) + acc + bias        (Wo, W2 mid)
// MODE 4: Cf32  = b2f(Cin) + acc + bias        (W2 final -> o_h)
// STATS 1: accumulate per-row sum/sumsq of result into sums[m*2 +{0,1}]
template<int MODE, int STATS>
__global__ __launch_bounds__(256, 4) void gemm_mfma(
    const unsigned short* __restrict__ A, const unsigned short* __restrict__ Bt,
    const float* __restrict__ bias, void* __restrict__ Cv,
    const unsigned short* __restrict__ Cin, float* __restrict__ sums,
    int M, int N, int K)
{
    __shared__ __align__(16) unsigned short As[128*64];
    __shared__ __align__(16) unsigned short Bs[128*64];
    const int tid = threadIdx.x;
    const int w = tid >> 6, l = tid & 63;
    int bx, by; swz_tile(bx, by);
    const int m0 = by * 128, n0 = bx * 128;
    const int wr = w >> 1, wc = w & 1;
    GEMM_CORE(A, Bt, K)
    const int cn  = l & 15;
    const int cr4 = (l >> 4) * 4;
    float* slds = (float*)As;          // 2KB reuse, safe after final barrier
    float bnv[4];
    #pragma unroll
    for(int ni=0;ni<4;++ni) bnv[ni] = bias[n0 + wc*64 + ni*16 + cn];
    #pragma unroll
    for(int mi=0;mi<4;++mi){
        #pragma unroll
        for(int r=0;r<4;++r){
            int rb = wr*64 + mi*16 + cr4 + r;
            int m  = m0 + rb;
            float s1 = 0.f, s2 = 0.f;
            #pragma unroll
            for(int ni=0;ni<4;++ni){
                int n = n0 + wc*64 + ni*16 + cn;
                size_t off = (size_t)m*N + n;
                float v = b2f(Cin[off]) + acc[mi][ni][r] + bnv[ni];
                if(MODE == 1) ((unsigned short*)Cv)[off] = f2b(v);
                else          ((float*)Cv)[off] = v;
                if(STATS){ s1 += v; s2 += v*v; }
            }
            if(STATS) STATS_REDUCE_STORE(rb, s1, s2)
        }
    }
    if(STATS){
        __syncthreads();
        if(tid < 128){
            float t1 = slds[(tid*2+0)*2+0] + slds[(tid*2+1)*2+0];
            float t2 = slds[(tid*2+0)*2+1] + slds[(tid*2+1)*2+1];
            atomicAdd(&sums[(size_t)(m0+tid)*2],   t1);
            atomicAdd(&sums[(size_t)(m0+tid)*2+1], t2);
        }
    }
}

// ---------------- LN-folded MFMA GEMM (stats-consuming), register-capped -----
// GELU=0: Cbf16 = rs*acc - rs*mu*cvec + dvec          (qkv)
// GELU=1: Cbf16 = gelu(rs*acc - rs*mu*cvec + dvec)    (W1)
template<int GELU>
__global__ __launch_bounds__(256, 4) void gemm_ln(
    const unsigned short* __restrict__ A, const unsigned short* __restrict__ Bt,
    void* __restrict__ Cv, const float* __restrict__ sums,
    const float* __restrict__ cvec, const float* __restrict__ dvec,
    int M, int N, int K)
{
    __shared__ __align__(16) unsigned short As[128*64];
    __shared__ __align__(16) unsigned short Bs[128*64];
    const int tid = threadIdx.x;
    const int w = tid >> 6, l = tid & 63;
    int bx, by; swz_tile(bx, by);
    const int m0 = by * 128, n0 = bx * 128;
    const int wr = w >> 1, wc = w & 1;
    GEMM_CORE(A, Bt, K)
    const int cn  = l & 15;
    const int cr4 = (l >> 4) * 4;
    float cv[4], dv[4];
    #pragma unroll
    for(int ni=0;ni<4;++ni){
        int n = n0 + wc*64 + ni*16 + cn;
        cv[ni] = cvec[n]; dv[ni] = dvec[n];
    }
    #pragma unroll
    for(int mi=0;mi<4;++mi){
        #pragma unroll
        for(int r=0;r<4;++r){
            int m = m0 + wr*64 + mi*16 + cr4 + r;
            float mu  = sums[(size_t)m*2]   * (1.0f/256.0f);
            float ex2 = sums[(size_t)m*2+1] * (1.0f/256.0f);
            float rs = rsqrtf(ex2 - mu*mu + 1e-5f);
            float c0 = rs * mu;
            #pragma unroll
            for(int ni=0;ni<4;++ni){
                int n = n0 + wc*64 + ni*16 + cn;
                float y = rs*acc[mi][ni][r] - c0*cv[ni] + dv[ni];
                ((unsigned short*)Cv)[(size_t)m*N + n] = f2b(GELU ? gelu_f(y) : y);
            }
        }
    }
}

// ---------------- DFT GEMM: A reg-staged from x (frames fused) --------------
__global__ __launch_bounds__(256) void gemm_dft(
    const float* __restrict__ x, const unsigned short* __restrict__ Bt,
    unsigned short* __restrict__ spec)
{
    const int K = 256;
    __shared__ __align__(16) unsigned short As[128*64];
    __shared__ __align__(16) unsigned short Bs[128*64];
    const int tid = threadIdx.x;
    const int w = tid >> 6, l = tid & 63;
    int bx, by; swz_tile(bx, by);
    const int m0 = by * 128, n0 = bx * 128;
    const int wr = w >> 1, wc = w & 1;
    f32x4 acc[4][4];
    #pragma unroll
    for(int i=0;i<4;++i)
        #pragma unroll
        for(int jj=0;jj<4;++jj) acc[i][jj] = (f32x4){0.f,0.f,0.f,0.f};
    const int sgrp = l & 7;
    for(int k0 = 0; k0 < K; k0 += 64){
        #pragma unroll
        for(int it=0; it<4; ++it){
            int row = w*32 + it*8 + (l>>3);
            int kg  = sgrp ^ (row & 7);
            int kb  = k0 + kg*8;
            int m   = m0 + row;
            int t   = m % TT;
            long bc = m / TT;
            const float* src = x + bc*(long)TSLEN + (long)t*HOPSZ + kb;
            u16x8 v;
            #pragma unroll
            for(int j=0;j<8;++j){
                float f = (kb + j < NFFT) ? src[j] : 0.f;
                v[j] = f2b(f);
            }
            *(u16x8*)&As[row*64 + sgrp*8] = v;
            int colB = (kg << 3);
            const unsigned short* gb = Bt + (size_t)(n0+row)*K + k0 + colB;
            __builtin_amdgcn_global_load_lds(
                (__attribute__((address_space(1))) void*)gb,
                (__attribute__((address_space(3))) void*)(Bs + w*2048 + it*512),
                16, 0, 0);
        }
        __syncthreads();
        GEMM_MFMA_PHASE
        __syncthreads();
    }
    const int cn  = l & 15;
    const int cr4 = (l >> 4) * 4;
    #pragma unroll
    for(int ni=0;ni<4;++ni){
        int n = n0 + wc*64 + ni*16 + cn;
        #pragma unroll
        for(int mi=0;mi<4;++mi){
            int mB = m0 + wr*64 + mi*16 + cr4;
            #pragma unroll
            for(int r=0;r<4;++r){
                float own = acc[mi][ni][r];
                float par = __shfl_xor(own, 1, 64);
                if(!(cn & 1)){
                    float sv = sqrtf(own*own + par*par);
                    spec[(size_t)(mB+r)*128 + (n >> 1)] = f2b(sv);
                }
            }
        }
    }
}

// ---------------- emb GEMM: spec_b @ Wpb + fused epilogue + LN stats ---------
__global__ __launch_bounds__(256) void gemm_emb(
    const unsigned short* __restrict__ A, const unsigned short* __restrict__ Bt,
    const float* __restrict__ bp, const float* __restrict__ ctok,
    const float* __restrict__ pe, const float* __restrict__ noise,
    float* __restrict__ o_emb, float* __restrict__ o_masked,
    float* __restrict__ o_mask, unsigned short* __restrict__ bufH,
    float* __restrict__ sums)
{
    const int K = 128, N = 256;
    __shared__ __align__(16) unsigned short As[128*64];
    __shared__ __align__(16) unsigned short Bs[128*64];
    const int tid = threadIdx.x;
    const int w = tid >> 6, l = tid & 63;
    int bx, by; swz_tile(bx, by);
    const int m0 = by * 128, n0 = bx * 128;
    const int wr = w >> 1, wc = w & 1;
    GEMM_CORE(A, Bt, K)
    const int cn  = l & 15;
    const int cr4 = (l >> 4) * 4;
    float* slds = (float*)As;
    float bnv[4];
    #pragma unroll
    for(int ni=0;ni<4;++ni) bnv[ni] = bp[n0 + wc*64 + ni*16 + cn];
    #pragma unroll
    for(int mi=0;mi<4;++mi){
        #pragma unroll
        for(int r=0;r<4;++r){
            int rb = wr*64 + mi*16 + cr4 + r;
            int m  = m0 + rb;
            int t = m % TT;
            int c = (m / TT) % NCH;
            float s1 = 0.f, s2 = 0.f;
            #pragma unroll
            for(int ni=0;ni<4;++ni){
                int n = n0 + wc*64 + ni*16 + cn;
                size_t off = (size_t)m*EMBD + n;
                float v = acc[mi][ni][r] + bnv[ni] + ctok[c*EMBD + n] + pe[t*EMBD + n];
                o_emb[off] = v;
                float mn = noise[off];
                bool  msk = mn < 0.9f;
                float md = msk ? 0.f : v;
                bufH[off]     = f2b(md);
                o_masked[off] = md;
                o_mask[off]   = msk ? 1.f : 0.f;
                s1 += md; s2 += md*md;
            }
            STATS_REDUCE_STORE(rb, s1, s2)
        }
    }
    __syncthreads();
    if(tid < 128){
        float t1 = slds[(tid*2+0)*2+0] + slds[(tid*2+1)*2+0];
        float t2 = slds[(tid*2+0)*2+1] + slds[(tid*2+1)*2+1];
        atomicAdd(&sums[(size_t)(m0+tid)*2],   t1);
        atomicAdd(&sums[(size_t)(m0+tid)*2+1], t2);
    }
}

// ---------------- ctx with fused k-softmax stats -----------------------------
__global__ __launch_bounds__(256) void ctx_kernel(const unsigned short* __restrict__ qkvb,
    float* __restrict__ ctx)
{
    __shared__ float kt[16][DH], vt[16][DH];
    __shared__ float sm[8][32], ss[8][32];
    __shared__ float kmsL[32], kinvL[32];
    int bh = blockIdx.x; int b = bh >> 3, h = bh & 7;
    int tid = threadIdx.x;
    {
        int d = tid & 31, g = tid >> 5;
        const unsigned short* p = qkvb + (size_t)b*SS*QKVW + 256 + h*DH + d;
        float m = -1e30f, s = 0.f;
        for(int n = g; n < SS; n += 8){
            float xv = b2f(p[(size_t)n*QKVW]);
            if(xv > m){ s = s*expf(m-xv) + 1.f; m = xv; }
            else      { s += expf(xv-m); }
        }
        sm[g][d] = m; ss[g][d] = s;
    }
    __syncthreads();
    if(tid < 32){
        float M = sm[0][tid], S = ss[0][tid];
        #pragma unroll
        for(int o = 1; o < 8; ++o){
            float m2 = sm[o][tid], s2 = ss[o][tid];
            if(m2 > M){ S = S*expf(M-m2) + s2; M = m2; }
            else      { S += s2*expf(m2-M); }
        }
        kmsL[tid] = M; kinvL[tid] = 1.0f / S;
    }
    __syncthreads();
    int d = tid >> 3, e4 = (tid & 7) * 4;
    float km = kmsL[d];
    float a0=0,a1=0,a2=0,a3=0;
    for(int n0=0;n0<SS;n0+=16){
        __syncthreads();
        #pragma unroll
        for(int i=0;i<2;++i){
            int e = tid + i*256;
            int nn = e >> 5, dd = e & 31;
            int n = n0 + nn;
            float kv, vv;
            if(n < SS){
                size_t off = ((size_t)(b*SS+n))*QKVW + h*DH + dd;
                kv = b2f(qkvb[off + 256]);
                vv = b2f(qkvb[off + 512]);
            } else { kv = -1e30f; vv = 0.f; }
            kt[nn][dd] = kv; vt[nn][dd] = vv;
        }
        __syncthreads();
        #pragma unroll
        for(int nn=0;nn<16;++nn){
            float ke = expf(kt[nn][d] - km);
            a0 = fmaf(ke, vt[nn][e4+0], a0);
            a1 = fmaf(ke, vt[nn][e4+1], a1);
            a2 = fmaf(ke, vt[nn][e4+2], a2);
            a3 = fmaf(ke, vt[nn][e4+3], a3);
        }
    }
    float inv = kinvL[d];
    float* op = ctx + ((size_t)bh*DH + d)*DH + e4;
    op[0]=a0*inv; op[1]=a1*inv; op[2]=a2*inv; op[3]=a3*inv;
}

// ---------------- per-token q-softmax + att = q @ ctx -> bf16 ----------------
__global__ __launch_bounds__(256) void att_kernel(const unsigned short* __restrict__ qkvb,
    const float* __restrict__ ctx, unsigned short* __restrict__ att)
{
    __shared__ float qs[4][EMBD];
    int w = threadIdx.x >> 6, lane = threadIdx.x & 63;
    int b = blockIdx.y;
    int s = blockIdx.x*4 + w;
    if(s >= SS) return;
    long row = (long)b*SS + s;
    ushort4 qu = *(const ushort4*)(qkvb + (size_t)row*QKVW + lane*4);
    float4 q4 = make_float4(b2f(qu.x), b2f(qu.y), b2f(qu.z), b2f(qu.w));
    float m = fmaxf(fmaxf(q4.x,q4.y), fmaxf(q4.z,q4.w));
    #pragma unroll
    for(int o=1;o<8;o<<=1) m = fmaxf(m, __shfl_xor(m, o, 64));
    float e0 = expf(q4.x-m), e1 = expf(q4.y-m), e2 = expf(q4.z-m), e3 = expf(q4.w-m);
    float ssum = e0+e1+e2+e3;
    #pragma unroll
    for(int o=1;o<8;o<<=1) ssum += __shfl_xor(ssum, o, 64);
    float sc = 0.17677669529663687f / ssum;
    *(float4*)&qs[w][lane*4] = make_float4(e0*sc, e1*sc, e2*sc, e3*sc);
    int head = lane >> 3;
    int ecol = (lane & 7) * 4;
    const float* cb = ctx + ((size_t)(b*NHEAD + head))*DH*DH + ecol;
    float a0=0,a1=0,a2=0,a3=0;
    #pragma unroll
    for(int d=0; d<DH; ++d){
        float qd = qs[w][head*DH + d];
        float4 c4 = *(const float4*)(cb + d*DH);
        a0 = fmaf(qd, c4.x, a0);
        a1 = fmaf(qd, c4.y, a1);
        a2 = fmaf(qd, c4.z, a2);
        a3 = fmaf(qd, c4.w, a3);
    }
    ushort4 o4; o4.x=f2b(a0); o4.y=f2b(a1); o4.z=f2b(a2); o4.w=f2b(a3);
    *(ushort4*)(att + row*EMBD + lane*4) = o4;
}

// ---------------- launch ----------------
extern "C" void kernel_launch(void* const* d_in, const int* in_sizes, int n_in,
                              void* d_out, int out_size, void* d_ws, size_t ws_size,
                              hipStream_t stream)
{
    if(n_in != 18) return;

    const float* x     = (const float*)d_in[0];
    const float* noise = (const float*)d_in[1];
    const float* Wproj = (const float*)d_in[2];
    const float* bproj = (const float*)d_in[3];
    const float* ctok  = (const float*)d_in[4];
    const float* ln1s  = (const float*)d_in[5];
    const float* ln1b  = (const float*)d_in[6];
    const float* Wq    = (const float*)d_in[7];
    const float* Wk    = (const float*)d_in[8];
    const float* Wv    = (const float*)d_in[9];
    const float* Wo    = (const float*)d_in[10];
    const float* bo    = (const float*)d_in[11];
    const float* ln2s  = (const float*)d_in[12];
    const float* ln2b  = (const float*)d_in[13];
    const float* W1    = (const float*)d_in[14];
    const float* b1    = (const float*)d_in[15];
    const float* W2    = (const float*)d_in[16];
    const float* b2    = (const float*)d_in[17];

    char* p = (char*)d_ws;
    unsigned short* bufHb = (unsigned short*)p;           p += (size_t)NTOK*2;
    float* big = (float*)p;                               p += (size_t)NTOK*2*4;
    unsigned short* qkvb   = (unsigned short*)big;        // bf16 [BSR][768]
    unsigned short* hidb   = (unsigned short*)big;        // bf16 [BSR][1024]
    unsigned short* specb  = (unsigned short*)p;          p += (size_t)BSR*128*2;
    unsigned short* attb   = (unsigned short*)p;          p += (size_t)NTOK*2;
    float* sums1 = (float*)p;                             p += (size_t)BSR*2*4;  // ln1 stats
    float* sums2 = (float*)p;                             p += (size_t)BSR*2*4;  // ln2 stats
    float* cdb  = (float*)p;                              p += (size_t)NDEPTH*CDL*4;
    float* ctxb = (float*)p;                              p += (size_t)BB*NHEAD*DH*DH*4;
    float* peb  = (float*)p;                              p += (size_t)TT*EMBD*4;
    unsigned short* twb  = (unsigned short*)p;            p += (size_t)65536*2;
    unsigned short* Wpb  = (unsigned short*)p;            p += (size_t)32768*2;
    unsigned short* wbuf = (unsigned short*)p;            p += (size_t)4*WL*2;
    if(ws_size < (size_t)(p - (char*)d_ws)) return;

    float* out      = (float*)d_out;
    float* o_emb    = out;
    float* o_masked = out + (size_t)NTOK;
    float* o_h      = out + 2*(size_t)NTOK;
    float* o_mask   = out + 3*(size_t)NTOK;

    dim3 blk(256);
    const size_t SB = (size_t)BSR*2*4;

    // ---- prep ----
    init_twb<<<256, blk, 0, stream>>>(twb);
    init_pe <<<19,  blk, 0, stream>>>(peb);
    wprep_proj<<<128, blk, 0, stream>>>(Wproj, Wpb);
    wprep_qkv<<<3072, blk, 0, stream>>>(Wq, Wk, Wv, ln1s, wbuf);
    wprep_wo <<<1024, blk, 0, stream>>>(Wo, wbuf);
    wprep_w1 <<<4096, blk, 0, stream>>>(W1, ln2s, wbuf);
    wprep_w2 <<<4096, blk, 0, stream>>>(W2, wbuf);
    prep_cd  <<<28,   blk, 0, stream>>>(Wq, Wk, Wv, W1, ln1s, ln1b, ln2s, ln2b, b1, cdb);

    // ---- front end ----
    hipMemsetAsync(sums1, 0, SB, stream);
    gemm_dft<<<dim3(2,874), blk, 0, stream>>>(x, twb, specb);
    gemm_emb<<<dim3(2,874), blk, 0, stream>>>(specb, Wpb, bproj, ctok, peb, noise,
                                              o_emb, o_masked, o_mask, bufHb, sums1);

    // ---- transformer layers (LN folded; stats fused into producer GEMMs) ----
    for(int l=0;l<NDEPTH;++l){
        unsigned short* wl   = wbuf + (size_t)l*WL;
        unsigned short* Wqkv = wl;             // [768][256], ln1s-folded
        unsigned short* Wot  = wl + 196608;    // [256][256]
        unsigned short* W1t  = wl + 262144;    // [1024][256], ln2s-folded
        unsigned short* W2t  = wl + 524288;    // [256][1024]
        float* cq = cdb + (size_t)l*CDL;
        float* dq = cq + 768;
        float* c1 = cq + 1536;
        float* d1 = cq + 2560;

        gemm_ln<0><<<dim3(6,874), blk, 0, stream>>>(bufHb, Wqkv, qkvb,
                                    sums1, cq, dq, BSR, QKVW, EMBD);
        ctx_kernel<<<BB*NHEAD, blk, 0, stream>>>(qkvb, ctxb);
        att_kernel<<<dim3(110, BB), blk, 0, stream>>>(qkvb, ctxb, attb);
        hipMemsetAsync(sums2, 0, SB, stream);
        gemm_mfma<1,1><<<dim3(2,874), blk, 0, stream>>>(attb, Wot, bo + l*EMBD, bufHb,
                                    bufHb, sums2, BSR, EMBD, EMBD);
        gemm_ln<1><<<dim3(8,874), blk, 0, stream>>>(bufHb, W1t, hidb,
                                    sums2, c1, d1, BSR, HID, EMBD);
        if(l == NDEPTH-1){
            gemm_mfma<4,0><<<dim3(2,874), blk, 0, stream>>>(hidb, W2t, b2 + l*EMBD, o_h,
                                    bufHb, nullptr, BSR, EMBD, HID);
        } else {
            hipMemsetAsync(sums1, 0, SB, stream);
            gemm_mfma<1,1><<<dim3(2,874), blk, 0, stream>>>(hidb, W2t, b2 + l*EMBD, bufHb,
                                    bufHb, sums1, BSR, EMBD, HID);
        }
    }
}